// Round 5
// baseline (305.551 us; speedup 1.0000x reference)
//
#include <hip/hip_runtime.h>

#define BB 8
#define NN 128
#define ND 64
#define LL 512
#define RD 1024
#define CG 128
#define CP 128
#define HID 192

typedef __attribute__((ext_vector_type(8))) short short8;
typedef __attribute__((ext_vector_type(4))) float f32x4;

__device__ __forceinline__ unsigned short f2bf(float x) {
    unsigned u = __builtin_bit_cast(unsigned, x);
    u += 0x7fffu + ((u >> 16) & 1u);          // RNE
    return (unsigned short)(u >> 16);
}

// device-wide soft barrier: every block arrives once; t0 spins; all release.
// bar must be zeroed before kernel launch (k1 does it, stream-ordered).
__device__ __forceinline__ void gbar(unsigned* bar, unsigned target, int t) {
    __threadfence();
    __syncthreads();
    if (t == 0) {
        atomicAdd(bar, 1u);
        while (atomicAdd(bar, 0u) < target) __builtin_amdgcn_s_sleep(8);
    }
    __syncthreads();
    __threadfence();
}

// ---------------------------------------------------------------------------
// K1 (grid 2561 x 256):
//  blk <256   : h0 = nodes@Wn + bn ; norm = rsqrt(max(deg,1))
//  blk ==256  : vbuf = W2@Wo ; b1c = b1 + br@W1b ; cconst ; acc=0; ctr=0; bars=0
//  257..512   : WcT[c][k] = bf16( (Wr@W1b)[k][c] )   (4 k-rows per block)
//  513..2560  : protb = bf16(prot)  (2048 elems per block)
// ---------------------------------------------------------------------------
__global__ __launch_bounds__(256) void k1_prep(
    const float* __restrict__ adj, const float* __restrict__ nodes,
    const float* __restrict__ prot,
    const float* __restrict__ Wn, const float* __restrict__ bn,
    const float* __restrict__ Wr, const float* __restrict__ br,
    const float* __restrict__ W1, const float* __restrict__ b1,
    const float* __restrict__ W2, const float* __restrict__ b2,
    const float* __restrict__ Wo, const float* __restrict__ bo,
    float* __restrict__ hA, float* __restrict__ normb,
    float* __restrict__ vbuf, float* __restrict__ cconst,
    float* __restrict__ acc, unsigned* __restrict__ ctr,
    unsigned* __restrict__ bars,
    unsigned short* __restrict__ WcT, float* __restrict__ b1c,
    unsigned short* __restrict__ protb)
{
    int t = threadIdx.x;
    int blk = blockIdx.x;
    const float* W1b = W1 + CG * HID;
    if (blk >= 513) {
        size_t base = (size_t)(blk - 513) * 2048 + (size_t)t * 8;
        float4 p0 = *(const float4*)(prot + base);
        float4 p1 = *(const float4*)(prot + base + 4);
        unsigned short o[8];
        o[0] = f2bf(p0.x); o[1] = f2bf(p0.y); o[2] = f2bf(p0.z); o[3] = f2bf(p0.w);
        o[4] = f2bf(p1.x); o[5] = f2bf(p1.y); o[6] = f2bf(p1.z); o[7] = f2bf(p1.w);
        *(short8*)(protb + base) = *(const short8*)o;
        return;
    }
    if (blk == 256) {
        if (t < HID) {
            float s = 0.f;
            for (int k = 0; k < CG; ++k) s = fmaf(W2[t * CG + k], Wo[k], s);
            vbuf[t] = s;
            float sb = 0.f;
            for (int m = 0; m < CG; ++m) sb = fmaf(br[m], W1b[m * HID + t], sb);
            b1c[t] = b1[t] + sb;
        }
        if (t == 255) {
            float s = 0.f;
            for (int k = 0; k < CG; ++k) s = fmaf(b2[k], Wo[k], s);
            cconst[0] = (float)(NN * LL) * s + bo[0];
        }
        if (t == 254) *ctr = 0u;
        if (t < 3) bars[t] = 0u;
        if (t < BB) acc[t] = 0.f;
        return;
    }
    if (blk > 256) {
        int r0 = (blk - 257) * 4;
        __shared__ float sW[4][CG];
        if (t < 128) ((float4*)&sW[0][0])[t] = ((const float4*)(Wr + (size_t)r0 * CG))[t];
        __syncthreads();
        #pragma unroll
        for (int q = 0; q < 3; ++q) {
            int o = q * 256 + t;            // 0..767
            int r = o / HID, c = o % HID;
            float s = 0.f;
            for (int m = 0; m < CG; ++m) s = fmaf(sW[r][m], W1b[m * HID + c], s);
            WcT[(size_t)c * RD + r0 + r] = f2bf(s);
        }
        return;
    }
    int b = blk >> 5;           // 32 blocks per batch
    int n0 = (blk & 31) * 4;    // 4 rows per block
    __shared__ float sn[4][ND];
    sn[t >> 6][t & 63] = nodes[(b * NN + n0 + (t >> 6)) * ND + (t & 63)];
    __syncthreads();
    {
        int w = t >> 6, lane = t & 63;
        const float* ar = adj + (size_t)(b * NN + n0 + w) * NN;
        float d = ar[lane] + ar[lane + 64];
        for (int off = 32; off; off >>= 1) d += __shfl_down(d, off);
        if (lane == 0) normb[b * NN + n0 + w] = rsqrtf(fmaxf(d, 1.0f));
    }
    int c = t & 127, rr = t >> 7;   // rows rr and rr+2
    float a0 = bn[c], a1 = bn[c];
    for (int k = 0; k < ND; ++k) {
        float wv = Wn[k * CG + c];
        a0 = fmaf(sn[rr][k], wv, a0);
        a1 = fmaf(sn[rr + 2][k], wv, a1);
    }
    hA[(b * NN + n0 + rr) * CG + c] = a0;
    hA[(b * NN + n0 + rr + 2) * CG + c] = a1;
}

// ---------------------------------------------------------------------------
// K3: partial rW1 = protb @ WcT^T over a K-half (512). No bias (in b1c).
// block = 256 thr (4 waves); wave owns 16 rows x 48 cols; grid 512 (2/SIMD)
// ---------------------------------------------------------------------------
__global__ __launch_bounds__(256) void k3_mfma(
    const unsigned short* __restrict__ protb, const unsigned short* __restrict__ WcT,
    float* __restrict__ rWp)
{
    int t = threadIdx.x;
    int w = t >> 6, l = t & 63;
    int kh = blockIdx.x & 1;
    int cb = (blockIdx.x >> 1) & 3;
    int rb = blockIdx.x >> 3;
    int r0 = rb * 64 + w * 16;
    int c0 = cb * 48;
    int lr = l & 15;
    int lk = (l >> 4) * 8;
    const unsigned short* ap = protb + (size_t)(r0 + lr) * RD + kh * 512 + lk;
    const unsigned short* bp = WcT + (size_t)(c0 + lr) * RD + kh * 512 + lk;
    f32x4 a0 = {0.f, 0.f, 0.f, 0.f}, a1 = a0, a2 = a0;
    #pragma unroll 4
    for (int k0 = 0; k0 < 512; k0 += 32) {
        short8 av = *(const short8*)(ap + k0);
        short8 b0 = *(const short8*)(bp + k0);
        short8 b1 = *(const short8*)(bp + 16 * RD + k0);
        short8 b2 = *(const short8*)(bp + 32 * RD + k0);
        a0 = __builtin_amdgcn_mfma_f32_16x16x32_bf16(av, b0, a0, 0, 0, 0);
        a1 = __builtin_amdgcn_mfma_f32_16x16x32_bf16(av, b1, a1, 0, 0, 0);
        a2 = __builtin_amdgcn_mfma_f32_16x16x32_bf16(av, b2, a2, 0, 0, 0);
    }
    int orow = r0 + (l >> 4) * 4;
    float* base = rWp + (size_t)kh * (4096 * HID);
    #pragma unroll
    for (int i = 0; i < 4; ++i) {
        float* cr = base + (size_t)(orow + i) * HID + c0 + lr;
        cr[0]  = a0[i];
        cr[16] = a1[i];
        cr[32] = a2[i];
    }
}

// ---------------------------------------------------------------------------
// K2F: fused 3 GNN steps (+hW1) + pairsum + final output.
// grid 256 x 512 thr (co-resident: 2048 waves << 8192; 34KB LDS).
// soft barriers: bars[0] after step0, bars[1] after step1, bars[2] after hW1.
// ---------------------------------------------------------------------------
__global__ __launch_bounds__(512) void k2f_gnn_pairsum(
    const float* __restrict__ adj, const float* __restrict__ Wg,
    const float* __restrict__ bg, const float* __restrict__ normb,
    float* hA, float* hB,
    const float* __restrict__ W1, const float* __restrict__ b1c,
    float* __restrict__ hW1,
    const float* __restrict__ rWa, const float* __restrict__ rWb,
    const float* __restrict__ vbuf, float* __restrict__ acc,
    const float* __restrict__ cconst, unsigned* __restrict__ ctr,
    unsigned* __restrict__ bars, float* __restrict__ out)
{
    int t = threadIdx.x;
    int blk = blockIdx.x;
    int b = blk >> 5;
    int i0 = (blk & 31) * 4;
    __shared__ float hs[64][CG];    // 32KB
    __shared__ float ms[4][CG];
    int c = t & 127;
    int ib = t >> 7;                // 0..3 (one row per thread)

    for (int s = 0; s < 3; ++s) {
        const float* hin = (s == 1) ? hB : hA;
        float* hout = (s == 1) ? hA : hB;
        float m = 0.f;
        const float* hbase = hin + (size_t)b * NN * CG;
        for (int half = 0; half < 2; ++half) {
            __syncthreads();
            #pragma unroll
            for (int q = 0; q < 4; ++q) {
                int f4 = t + 512 * q;        // 0..2047
                int row = f4 >> 5;           // 0..63
                int col4 = (f4 & 31) * 4;
                float4 hv = *(const float4*)(hbase + (half * 64 + row) * CG + col4);
                float nv = normb[b * NN + half * 64 + row];
                hv.x *= nv; hv.y *= nv; hv.z *= nv; hv.w *= nv;
                *(float4*)(&hs[row][col4]) = hv;
            }
            __syncthreads();
            const float* arow = adj + (size_t)(b * NN + i0 + ib) * NN + half * 64;
            for (int j = 0; j < 64; ++j)
                m = fmaf(arow[j], hs[j][c], m);
        }
        ms[ib][c] = m * normb[b * NN + i0 + ib];
        __syncthreads();
        float acc2 = bg[c];
        for (int k = 0; k < CG; ++k)
            acc2 = fmaf(ms[ib][k], Wg[k * CG + c], acc2);
        if (s < 2) {
            hout[(size_t)(b * NN + i0 + ib) * CG + c] = fmaxf(acc2, 0.f);
            gbar(bars + s, 256, t);
        } else {
            float* hn = &hs[0][0];   // reuse (4*128 floats)
            __syncthreads();         // everyone done reading hs from the step
            hn[ib * CG + c] = tanhf(acc2);
            __syncthreads();
            #pragma unroll
            for (int q = 0; q < 2; ++q) {
                int o = t + 512 * q;
                if (o < 4 * HID) {
                    int i = o / HID, jj = o % HID;
                    float sacc = b1c[jj];
                    for (int k = 0; k < CG; ++k)
                        sacc = fmaf(hn[i * CG + k], W1[k * HID + jj], sacc);
                    hW1[(size_t)(b * NN + i0 + i) * HID + jj] = sacc;
                }
            }
            gbar(bars + 2, 256, t);
        }
    }

    // ---- pairsum phase: 2 units per block (512 units total) ----
    int u = t >> 8;              // 0/1
    int tl = t & 255;
    int gu = blk * 2 + u;        // 0..511
    int pb = gu >> 6;            // batch
    int ns = (gu >> 3) & 7;      // 16-row n range
    int lt = gu & 7;             // 64-wide l tile
    int wv = tl >> 6;            // j-quarter
    int lane = tl & 63;
    int j0 = wv * 48;
    int l = lt * 64 + lane;
    float r[48], v[48];
    const float* rpa = rWa + ((size_t)pb * LL + l) * HID + j0;
    const float* rpb = rWb + ((size_t)pb * LL + l) * HID + j0;
    const float* vp = vbuf + j0;
    #pragma unroll
    for (int q = 0; q < 12; ++q) {
        float4 f = *(const float4*)(rpa + q * 4);
        float4 g = *(const float4*)(rpb + q * 4);
        r[q * 4 + 0] = f.x + g.x; r[q * 4 + 1] = f.y + g.y;
        r[q * 4 + 2] = f.z + g.z; r[q * 4 + 3] = f.w + g.w;
    }
    #pragma unroll
    for (int q = 0; q < 12; ++q) {
        float4 f = *(const float4*)(vp + q * 4);
        v[q * 4 + 0] = f.x; v[q * 4 + 1] = f.y; v[q * 4 + 2] = f.z; v[q * 4 + 3] = f.w;
    }
    float a0 = 0.f, a1 = 0.f, a2 = 0.f, a3 = 0.f;
    const float* hp = hW1 + ((size_t)pb * NN + ns * 16) * HID + j0;
    for (int n = 0; n < 16; ++n) {
        float hv[48];
        #pragma unroll
        for (int q = 0; q < 12; ++q) {
            float4 f = *(const float4*)(hp + n * HID + q * 4);
            hv[q * 4 + 0] = f.x; hv[q * 4 + 1] = f.y; hv[q * 4 + 2] = f.z; hv[q * 4 + 3] = f.w;
        }
        #pragma unroll
        for (int j = 0; j < 48; j += 4) {
            a0 = fmaf(v[j + 0], fmaxf(hv[j + 0] + r[j + 0], 0.f), a0);
            a1 = fmaf(v[j + 1], fmaxf(hv[j + 1] + r[j + 1], 0.f), a1);
            a2 = fmaf(v[j + 2], fmaxf(hv[j + 2] + r[j + 2], 0.f), a2);
            a3 = fmaf(v[j + 3], fmaxf(hv[j + 3] + r[j + 3], 0.f), a3);
        }
    }
    float a = (a0 + a1) + (a2 + a3);
    for (int off = 32; off; off >>= 1) a += __shfl_down(a, off);
    __shared__ float sred[2][4];
    __shared__ int lastf;
    if (lane == 0) sred[u][wv] = a;
    __syncthreads();
    if (t == 0) {
        float tot = (sred[0][0] + sred[0][1]) + (sred[0][2] + sred[0][3])
                  + (sred[1][0] + sred[1][1]) + (sred[1][2] + sred[1][3]);
        atomicAdd(&acc[pb], tot);   // both units share pb
        __threadfence();
        unsigned old = atomicAdd(ctr, 1u);
        lastf = (old == gridDim.x - 1) ? 1 : 0;
    }
    __syncthreads();
    if (lastf && t < BB)
        out[t] = atomicAdd(&acc[t], 0.0f) + cconst[0];
}

extern "C" void kernel_launch(void* const* d_in, const int* in_sizes, int n_in,
                              void* d_out, int out_size, void* d_ws, size_t ws_size,
                              hipStream_t stream)
{
    const float* adj   = (const float*)d_in[0];
    const float* nodes = (const float*)d_in[1];
    const float* prot  = (const float*)d_in[2];
    const float* Wn    = (const float*)d_in[3];
    const float* bn    = (const float*)d_in[4];
    const float* Wg    = (const float*)d_in[5];
    const float* bg    = (const float*)d_in[6];
    const float* Wr    = (const float*)d_in[7];
    const float* br    = (const float*)d_in[8];
    // d_in[9]=Wa, d_in[10]=ba: unused (softmax over size-1 axis == 1)
    const float* W1    = (const float*)d_in[11];
    const float* b1    = (const float*)d_in[12];
    const float* W2    = (const float*)d_in[13];
    const float* b2    = (const float*)d_in[14];
    const float* Wo    = (const float*)d_in[15];
    const float* bo    = (const float*)d_in[16];

    float* ws     = (float*)d_ws;
    float* hA     = ws;                        // [8][128][128]
    float* hB     = ws + 131072;               // [8][128][128]
    float* normb  = ws + 262144;               // [8][128]
    float* hW1b   = ws + 263168;               // [8][128][192]
    float* rWa    = ws + 459776;               // [4096][192] K-half 0
    float* rWb    = ws + 1246208;              // [4096][192] K-half 1
    float* vbuf   = ws + 2032640;              // [192]
    float* cconst = ws + 2032832;              // [1]
    float* accb   = ws + 2032836;              // [8]
    float* b1c    = ws + 2032844;              // [192]
    unsigned* ctr = (unsigned*)(ws + 2033036); // [1]
    unsigned* bars= (unsigned*)(ws + 2033037); // [3]
    unsigned short* protb = (unsigned short*)(ws + 2033040); // [4096][1024] bf16
    unsigned short* WcT   = (unsigned short*)(ws + 4130192); // [192][1024] bf16
    float* out    = (float*)d_out;

    hipLaunchKernelGGL(k1_prep, dim3(2561), dim3(256), 0, stream,
                       adj, nodes, prot, Wn, bn, Wr, br, W1, b1, W2, b2, Wo, bo,
                       hA, normb, vbuf, cconst, accb, ctr, bars, WcT, b1c, protb);
    hipLaunchKernelGGL(k3_mfma, dim3(512), dim3(256), 0, stream, protb, WcT, rWa);
    hipLaunchKernelGGL(k2f_gnn_pairsum, dim3(256), dim3(512), 0, stream,
                       adj, Wg, bg, normb, hA, hB, W1, b1c, hW1b,
                       rWa, rWb, vbuf, accb, cconst, ctr, bars, out);
}

// Round 6
// 229.523 us; speedup vs baseline: 1.3312x; 1.3312x over previous
//
#include <hip/hip_runtime.h>

#define BB 8
#define NN 128
#define ND 64
#define LL 512
#define RD 1024
#define CG 128
#define CP 128
#define HID 192

typedef __attribute__((ext_vector_type(8))) short short8;
typedef __attribute__((ext_vector_type(4))) float f32x4;

__device__ __forceinline__ unsigned short f2bf(float x) {
    unsigned u = __builtin_bit_cast(unsigned, x);
    u += 0x7fffu + ((u >> 16) & 1u);          // RNE
    return (unsigned short)(u >> 16);
}

// Device-wide soft barrier. ONE atomic RMW per block (arrival), then t0
// polls with agent-scope atomic LOADS (no RMW serialization - R5's bug).
// bar zeroed by k1 each call (stream-ordered before the mega kernel).
__device__ __forceinline__ void gbar(unsigned* bar, unsigned target, int t) {
    __syncthreads();                      // drains vmcnt: block's stores in L2
    if (t == 0) {
        __threadfence();                  // release: write-back for cross-XCD
        atomicAdd(bar, 1u);
        while (__hip_atomic_load(bar, __ATOMIC_RELAXED,
                                 __HIP_MEMORY_SCOPE_AGENT) < target)
            __builtin_amdgcn_s_sleep(2);
        __threadfence();                  // acquire: invalidate stale L1/L2
    }
    __syncthreads();
}

// ---------------------------------------------------------------------------
// K1 (grid 2561 x 256):
//  blk <256   : h0 = nodes@Wn + bn ; norm = rsqrt(max(deg,1))
//  blk ==256  : vbuf = W2@Wo ; b1c = b1 + br@W1b ; cconst ; acc=0; ctr=0; bars=0
//  257..512   : WcT[c][k] = bf16( (Wr@W1b)[k][c] )   (4 k-rows per block)
//  513..2560  : protb = bf16(prot)  (2048 elems per block)
// ---------------------------------------------------------------------------
__global__ __launch_bounds__(256) void k1_prep(
    const float* __restrict__ adj, const float* __restrict__ nodes,
    const float* __restrict__ prot,
    const float* __restrict__ Wn, const float* __restrict__ bn,
    const float* __restrict__ Wr, const float* __restrict__ br,
    const float* __restrict__ W1, const float* __restrict__ b1,
    const float* __restrict__ W2, const float* __restrict__ b2,
    const float* __restrict__ Wo, const float* __restrict__ bo,
    float* __restrict__ hA, float* __restrict__ normb,
    float* __restrict__ vbuf, float* __restrict__ cconst,
    float* __restrict__ acc, unsigned* __restrict__ ctr,
    unsigned* __restrict__ bars,
    unsigned short* __restrict__ WcT, float* __restrict__ b1c,
    unsigned short* __restrict__ protb)
{
    int t = threadIdx.x;
    int blk = blockIdx.x;
    const float* W1b = W1 + CG * HID;
    if (blk >= 513) {
        size_t base = (size_t)(blk - 513) * 2048 + (size_t)t * 8;
        float4 p0 = *(const float4*)(prot + base);
        float4 p1 = *(const float4*)(prot + base + 4);
        unsigned short o[8];
        o[0] = f2bf(p0.x); o[1] = f2bf(p0.y); o[2] = f2bf(p0.z); o[3] = f2bf(p0.w);
        o[4] = f2bf(p1.x); o[5] = f2bf(p1.y); o[6] = f2bf(p1.z); o[7] = f2bf(p1.w);
        *(short8*)(protb + base) = *(const short8*)o;
        return;
    }
    if (blk == 256) {
        if (t < HID) {
            float s = 0.f;
            for (int k = 0; k < CG; ++k) s = fmaf(W2[t * CG + k], Wo[k], s);
            vbuf[t] = s;
            float sb = 0.f;
            for (int m = 0; m < CG; ++m) sb = fmaf(br[m], W1b[m * HID + t], sb);
            b1c[t] = b1[t] + sb;
        }
        if (t == 255) {
            float s = 0.f;
            for (int k = 0; k < CG; ++k) s = fmaf(b2[k], Wo[k], s);
            cconst[0] = (float)(NN * LL) * s + bo[0];
        }
        if (t == 254) *ctr = 0u;
        if (t < 3) bars[t] = 0u;
        if (t < BB) acc[t] = 0.f;
        return;
    }
    if (blk > 256) {
        int r0 = (blk - 257) * 4;
        __shared__ float sW[4][CG];
        if (t < 128) ((float4*)&sW[0][0])[t] = ((const float4*)(Wr + (size_t)r0 * CG))[t];
        __syncthreads();
        #pragma unroll
        for (int q = 0; q < 3; ++q) {
            int o = q * 256 + t;            // 0..767
            int r = o / HID, c = o % HID;
            float s = 0.f;
            for (int m = 0; m < CG; ++m) s = fmaf(sW[r][m], W1b[m * HID + c], s);
            WcT[(size_t)c * RD + r0 + r] = f2bf(s);
        }
        return;
    }
    int b = blk >> 5;           // 32 blocks per batch
    int n0 = (blk & 31) * 4;    // 4 rows per block
    __shared__ float sn[4][ND];
    sn[t >> 6][t & 63] = nodes[(b * NN + n0 + (t >> 6)) * ND + (t & 63)];
    __syncthreads();
    {
        int w = t >> 6, lane = t & 63;
        const float* ar = adj + (size_t)(b * NN + n0 + w) * NN;
        float d = ar[lane] + ar[lane + 64];
        for (int off = 32; off; off >>= 1) d += __shfl_down(d, off);
        if (lane == 0) normb[b * NN + n0 + w] = rsqrtf(fmaxf(d, 1.0f));
    }
    int c = t & 127, rr = t >> 7;   // rows rr and rr+2
    float a0 = bn[c], a1 = bn[c];
    for (int k = 0; k < ND; ++k) {
        float wv = Wn[k * CG + c];
        a0 = fmaf(sn[rr][k], wv, a0);
        a1 = fmaf(sn[rr + 2][k], wv, a1);
    }
    hA[(b * NN + n0 + rr) * CG + c] = a0;
    hA[(b * NN + n0 + rr + 2) * CG + c] = a1;
}

// ---------------------------------------------------------------------------
// MEGA kernel, grid 512 x 256 (2 blocks/CU guaranteed -> all co-resident):
//  phase A: MFMA tile of rW1 partials (same decomposition as R4 k3)
//  phase B: 3 GNN steps, 2 rows/block; barriers bars[0],bars[1] between
//           steps; step2 computes hW1 then bars[2]
//  phase C: pairsum unit (R4 k4), final output via ctr
// ---------------------------------------------------------------------------
__global__ __launch_bounds__(256, 2) void kmega(
    const unsigned short* __restrict__ protb, const unsigned short* __restrict__ WcT,
    float* __restrict__ rWp,
    const float* __restrict__ adj, const float* __restrict__ Wg,
    const float* __restrict__ bg, const float* __restrict__ normb,
    float* hA, float* hB,
    const float* __restrict__ W1, const float* __restrict__ b1c,
    float* __restrict__ hW1,
    const float* __restrict__ vbuf, float* __restrict__ acc,
    const float* __restrict__ cconst, unsigned* __restrict__ ctr,
    unsigned* __restrict__ bars, float* __restrict__ out)
{
    int t = threadIdx.x;
    int blk = blockIdx.x;

    // ---------------- phase A: MFMA (blk = 512 tiles) ----------------
    {
        int w = t >> 6, l = t & 63;
        int kh = blk & 1;
        int cb = (blk >> 1) & 3;
        int rb = blk >> 3;
        int r0 = rb * 64 + w * 16;
        int c0 = cb * 48;
        int lr = l & 15;
        int lk = (l >> 4) * 8;
        const unsigned short* ap = protb + (size_t)(r0 + lr) * RD + kh * 512 + lk;
        const unsigned short* bp = WcT + (size_t)(c0 + lr) * RD + kh * 512 + lk;
        f32x4 a0 = {0.f, 0.f, 0.f, 0.f}, a1 = a0, a2 = a0;
        #pragma unroll 4
        for (int k0 = 0; k0 < 512; k0 += 32) {
            short8 av = *(const short8*)(ap + k0);
            short8 b0 = *(const short8*)(bp + k0);
            short8 b1 = *(const short8*)(bp + 16 * RD + k0);
            short8 b2 = *(const short8*)(bp + 32 * RD + k0);
            a0 = __builtin_amdgcn_mfma_f32_16x16x32_bf16(av, b0, a0, 0, 0, 0);
            a1 = __builtin_amdgcn_mfma_f32_16x16x32_bf16(av, b1, a1, 0, 0, 0);
            a2 = __builtin_amdgcn_mfma_f32_16x16x32_bf16(av, b2, a2, 0, 0, 0);
        }
        int orow = r0 + (l >> 4) * 4;
        float* base = rWp + (size_t)kh * (4096 * HID);
        #pragma unroll
        for (int i = 0; i < 4; ++i) {
            float* cr = base + (size_t)(orow + i) * HID + c0 + lr;
            cr[0]  = a0[i];
            cr[16] = a1[i];
            cr[32] = a2[i];
        }
    }

    // ---------------- phase B: GNN, 2 rows per block ----------------
    __shared__ float hs[64][CG];    // 32KB
    __shared__ float ms[2][CG];
    {
        int b = blk >> 6;
        int i0 = (blk & 63) * 2;
        int c = t & 127;
        int ib = t >> 7;                // 0..1 (one row per thread)
        for (int s = 0; s < 3; ++s) {
            const float* hin = (s == 1) ? hB : hA;
            float* hout = (s == 1) ? hA : hB;
            float m = 0.f;
            const float* hbase = hin + (size_t)b * NN * CG;
            for (int half = 0; half < 2; ++half) {
                __syncthreads();
                #pragma unroll
                for (int q = 0; q < 8; ++q) {
                    int f4 = t + 256 * q;        // 0..2047
                    int row = f4 >> 5;           // 0..63
                    int col4 = (f4 & 31) * 4;
                    float4 hv = *(const float4*)(hbase + (half * 64 + row) * CG + col4);
                    float nv = normb[b * NN + half * 64 + row];
                    hv.x *= nv; hv.y *= nv; hv.z *= nv; hv.w *= nv;
                    *(float4*)(&hs[row][col4]) = hv;
                }
                __syncthreads();
                const float* arow = adj + (size_t)(b * NN + i0 + ib) * NN + half * 64;
                for (int j = 0; j < 64; ++j)
                    m = fmaf(arow[j], hs[j][c], m);
            }
            ms[ib][c] = m * normb[b * NN + i0 + ib];
            __syncthreads();
            float acc2 = bg[c];
            for (int k = 0; k < CG; ++k)
                acc2 = fmaf(ms[ib][k], Wg[k * CG + c], acc2);
            if (s < 2) {
                hout[(size_t)(b * NN + i0 + ib) * CG + c] = fmaxf(acc2, 0.f);
                gbar(bars + s, 512, t);
            } else {
                float* hn = &hs[0][0];   // reuse (2*128 floats)
                hn[ib * CG + c] = tanhf(acc2);
                __syncthreads();
                // hW1: 2 rows x 192 = 384 outputs; b1c folded
                #pragma unroll
                for (int q = 0; q < 2; ++q) {
                    int o = t + 256 * q;
                    if (o < 2 * HID) {
                        int i = o / HID, jj = o % HID;
                        float sacc = b1c[jj];
                        for (int k = 0; k < CG; ++k)
                            sacc = fmaf(hn[i * CG + k], W1[k * HID + jj], sacc);
                        hW1[(size_t)(b * NN + i0 + i) * HID + jj] = sacc;
                    }
                }
                gbar(bars + 2, 512, t);
            }
        }
    }

    // ---------------- phase C: pairsum (1 unit per block) ----------------
    const float* rWa = rWp;
    const float* rWb = rWp + (size_t)(4096 * HID);
    int pb = blk >> 6;          // batch
    int ns = (blk >> 3) & 7;    // 16-row n range
    int lt = blk & 7;           // 64-wide l tile
    int wv = t >> 6;            // j-quarter (48 dims)
    int lane = t & 63;
    int j0 = wv * 48;
    int l = lt * 64 + lane;
    float r[48], v[48];
    const float* rpa = rWa + ((size_t)pb * LL + l) * HID + j0;
    const float* rpb = rWb + ((size_t)pb * LL + l) * HID + j0;
    const float* vp = vbuf + j0;
    #pragma unroll
    for (int q = 0; q < 12; ++q) {
        float4 f = *(const float4*)(rpa + q * 4);
        float4 g = *(const float4*)(rpb + q * 4);
        r[q * 4 + 0] = f.x + g.x; r[q * 4 + 1] = f.y + g.y;
        r[q * 4 + 2] = f.z + g.z; r[q * 4 + 3] = f.w + g.w;
    }
    #pragma unroll
    for (int q = 0; q < 12; ++q) {
        float4 f = *(const float4*)(vp + q * 4);
        v[q * 4 + 0] = f.x; v[q * 4 + 1] = f.y; v[q * 4 + 2] = f.z; v[q * 4 + 3] = f.w;
    }
    float a0 = 0.f, a1 = 0.f, a2 = 0.f, a3 = 0.f;
    const float* hp = hW1 + ((size_t)pb * NN + ns * 16) * HID + j0;
    for (int n = 0; n < 16; ++n) {
        float hv[48];
        #pragma unroll
        for (int q = 0; q < 12; ++q) {
            float4 f = *(const float4*)(hp + n * HID + q * 4);
            hv[q * 4 + 0] = f.x; hv[q * 4 + 1] = f.y; hv[q * 4 + 2] = f.z; hv[q * 4 + 3] = f.w;
        }
        #pragma unroll
        for (int j = 0; j < 48; j += 4) {
            a0 = fmaf(v[j + 0], fmaxf(hv[j + 0] + r[j + 0], 0.f), a0);
            a1 = fmaf(v[j + 1], fmaxf(hv[j + 1] + r[j + 1], 0.f), a1);
            a2 = fmaf(v[j + 2], fmaxf(hv[j + 2] + r[j + 2], 0.f), a2);
            a3 = fmaf(v[j + 3], fmaxf(hv[j + 3] + r[j + 3], 0.f), a3);
        }
    }
    float a = (a0 + a1) + (a2 + a3);
    for (int off = 32; off; off >>= 1) a += __shfl_down(a, off);
    __shared__ float sred[4];
    __shared__ int lastf;
    if (lane == 0) sred[wv] = a;
    __syncthreads();
    if (t == 0) {
        atomicAdd(&acc[pb], (sred[0] + sred[1]) + (sred[2] + sred[3]));
        __threadfence();
        unsigned old = atomicAdd(ctr, 1u);
        lastf = (old == gridDim.x - 1) ? 1 : 0;
    }
    __syncthreads();
    if (lastf && t < BB)
        out[t] = atomicAdd(&acc[t], 0.0f) + cconst[0];
}

extern "C" void kernel_launch(void* const* d_in, const int* in_sizes, int n_in,
                              void* d_out, int out_size, void* d_ws, size_t ws_size,
                              hipStream_t stream)
{
    const float* adj   = (const float*)d_in[0];
    const float* nodes = (const float*)d_in[1];
    const float* prot  = (const float*)d_in[2];
    const float* Wn    = (const float*)d_in[3];
    const float* bn    = (const float*)d_in[4];
    const float* Wg    = (const float*)d_in[5];
    const float* bg    = (const float*)d_in[6];
    const float* Wr    = (const float*)d_in[7];
    const float* br    = (const float*)d_in[8];
    // d_in[9]=Wa, d_in[10]=ba: unused (softmax over size-1 axis == 1)
    const float* W1    = (const float*)d_in[11];
    const float* b1    = (const float*)d_in[12];
    const float* W2    = (const float*)d_in[13];
    const float* b2    = (const float*)d_in[14];
    const float* Wo    = (const float*)d_in[15];
    const float* bo    = (const float*)d_in[16];

    float* ws     = (float*)d_ws;
    float* hA     = ws;                        // [8][128][128]
    float* hB     = ws + 131072;               // [8][128][128]
    float* normb  = ws + 262144;               // [8][128]
    float* hW1b   = ws + 263168;               // [8][128][192]
    float* rWp    = ws + 459776;               // 2 x [4096][192] K-half partials
    float* vbuf   = ws + 2032640;              // [192]
    float* cconst = ws + 2032832;              // [1]
    float* accb   = ws + 2032836;              // [8]
    float* b1c    = ws + 2032844;              // [192]
    unsigned* ctr = (unsigned*)(ws + 2033036); // [1]
    unsigned* bars= (unsigned*)(ws + 2033037); // [3]
    unsigned short* protb = (unsigned short*)(ws + 2033040); // [4096][1024] bf16
    unsigned short* WcT   = (unsigned short*)(ws + 4130192); // [192][1024] bf16
    float* out    = (float*)d_out;

    hipLaunchKernelGGL(k1_prep, dim3(2561), dim3(256), 0, stream,
                       adj, nodes, prot, Wn, bn, Wr, br, W1, b1, W2, b2, Wo, bo,
                       hA, normb, vbuf, cconst, accb, ctr, bars, WcT, b1c, protb);
    hipLaunchKernelGGL(kmega, dim3(512), dim3(256), 0, stream,
                       protb, WcT, rWp, adj, Wg, bg, normb, hA, hB,
                       W1, b1c, hW1b, vbuf, accb, cconst, ctr, bars, out);
}